// Round 6
// baseline (416.617 us; speedup 1.0000x reference)
//
#include <hip/hip_runtime.h>
#include <stdint.h>

#define S 16384
#define D 4096
#define NE 64
#define CAP 320
#define WQ 4               // waves per block = K-quarters
#define KCH (D / WQ)       // 1024 K per wave
#define CH 64              // staged chunk: 32 rows x 64 floats = 8 KB
#define NCH (KCH / CH)     // 16 chunks per wave
#define NKS (D / 16)       // 256 total k-steps
#define K2ROWS 128
#define NB (S / K2ROWS)    // 128

typedef _Float16 f16x8 __attribute__((ext_vector_type(8)));
typedef float f32x16 __attribute__((ext_vector_type(16)));

__device__ __forceinline__ uint32_t rotl32(uint32_t v, int n) {
  return (v << n) | (v >> (32 - n));
}

// Bit-exact jax threefry for jax.random.uniform(jax.random.key(1), (S,), f32)
// under jax_threefry_partitionable=True. (Verified passing, absmax 0.0.)
__device__ uint32_t threefry_bits(int i) {
  const uint32_t k0 = 0u, k1 = 1u;
  const uint32_t ks2 = k0 ^ k1 ^ 0x1BD11BDAu;
  uint32_t x0 = 0u + k0;
  uint32_t x1 = (uint32_t)i + k1;
#define TFR(R) { x0 += x1; x1 = rotl32(x1, R); x1 ^= x0; }
  TFR(13) TFR(15) TFR(26) TFR(6)
  x0 += k1;  x1 += ks2 + 1u;
  TFR(17) TFR(29) TFR(16) TFR(24)
  x0 += ks2; x1 += k0 + 2u;
  TFR(13) TFR(15) TFR(26) TFR(6)
  x0 += k0;  x1 += k1 + 3u;
  TFR(17) TFR(29) TFR(16) TFR(24)
  x0 += k1;  x1 += ks2 + 4u;
  TFR(13) TFR(15) TFR(26) TFR(6)
  x0 += ks2; x1 += k0 + 5u;
#undef TFR
  return x0 ^ x1;
}

// ---- k0: pack W (64x4096 f32) into fp16 hi/lo MFMA B-fragments (verified).
// n-tile t, k-step ks: lane l holds col = 32t+(l&31), k = 16*ks + 8*(l>>5)+j.
// A uses the same k-bijection. Split: w = wh + wl*2^-12 (exact residual).
__global__ __launch_bounds__(256) void k0_packw(const float* __restrict__ Wg,
                                                f16x8* __restrict__ WH,
                                                f16x8* __restrict__ WL) {
  const int tid = blockIdx.x * 256 + threadIdx.x;  // 32768 = 256 ks * 2 t * 64 lanes
  const int lane = tid & 63;
  const int t = (tid >> 6) & 1;
  const int ks = tid >> 7;
  const int col = 32 * t + (lane & 31);
  const int k0 = ks * 16 + 8 * (lane >> 5);
  const float* wp = Wg + (size_t)col * D + k0;
  f16x8 h, l;
#pragma unroll
  for (int j = 0; j < 8; ++j) {
    const float w = wp[j];
    const _Float16 wh = (_Float16)w;
    const float r = (w - (float)wh) * 4096.0f;  // exact in f32
    h[j] = wh;
    l[j] = (_Float16)r;
  }
  WH[tid] = h;
  WL[tid] = l;
}

// Per-element fp32 -> fp16 hi/lo split (same arithmetic as all passing rounds).
#define CVT1(J, F)                                                     \
  { const float f_ = (F); const _Float16 h_ = (_Float16)f_;            \
    ah[J] = h_; al[J] = (_Float16)((f_ - (float)h_) * 4096.0f); }

// One k-step: convert 8 x-values, 6 MFMAs into flat accumulators.
#define KSTEP(X0, X1, BH0, BH1, BL0, BL1)                                    \
  {                                                                          \
    f16x8 ah, al;                                                            \
    CVT1(0, (X0).x) CVT1(1, (X0).y) CVT1(2, (X0).z) CVT1(3, (X0).w)          \
    CVT1(4, (X1).x) CVT1(5, (X1).y) CVT1(6, (X1).z) CVT1(7, (X1).w)          \
    acc00 = __builtin_amdgcn_mfma_f32_32x32x16_f16(ah, BH0, acc00, 0, 0, 0); \
    acc10 = __builtin_amdgcn_mfma_f32_32x32x16_f16(al, BH0, acc10, 0, 0, 0); \
    acc10 = __builtin_amdgcn_mfma_f32_32x32x16_f16(ah, BL0, acc10, 0, 0, 0); \
    acc01 = __builtin_amdgcn_mfma_f32_32x32x16_f16(ah, BH1, acc01, 0, 0, 0); \
    acc11 = __builtin_amdgcn_mfma_f32_32x32x16_f16(al, BH1, acc11, 0, 0, 0); \
    acc11 = __builtin_amdgcn_mfma_f32_32x32x16_f16(ah, BL1, acc11, 0, 0, 0); \
  }

// ---- k1: fused logits GEMM + softmax + top-2 + RNG.
// Fix for the stuck ~130us: the MFMA A-layout (row = lane&31) makes direct
// global A-loads a 32-segment/instruction gather (rows 16KB apart) -> TA
// request-rate bound; occupancy/ILP changes were null (r4/r5). Now x is
// staged through LDS: coalesced global loads (4 x 256B segments/instr),
// wave-private double-buffered [32][64] chunk with XOR bank swizzle
// (idx ^= (row&7)<<2 on BOTH ds_write and ds_read -> conflict-free), and
// ZERO barriers in the k-loop (per-wave buffers, lgkmcnt orders ds ops).
// Arithmetic, k-order and fold order are bit-identical to round-2's
// absmax-0.0 kernel. LDS = exactly 64 KB -> 2 blocks/CU, grid 512 = all
// resident.
__global__ __launch_bounds__(256) void k1_fused(const float* __restrict__ x,
                                                const f16x8* __restrict__ WH,
                                                const f16x8* __restrict__ WL,
                                                int* __restrict__ E1, int* __restrict__ E2,
                                                int* __restrict__ WANT,
                                                float* __restrict__ G1, float* __restrict__ G2) {
  __shared__ __align__(16) float xbuf[WQ][2][32][64];  // 64 KB exactly
  const int w = threadIdx.x >> 6;     // K-quarter 0..3
  const int lane = threadIdx.x & 63;
  const int rowBase = blockIdx.x * 32;
  // staging: lane -> (row group srow, 16B column scol); 4 rows x 256 B per instr
  const int srow = lane >> 4;         // 0..3
  const int scol = (lane & 15) * 4;   // float col 0..60
  // fragment: lane -> (A row, k half)
  const int arow = lane & 31;
  const int ahalf = lane >> 5;
  const int swzr = (arow & 7) << 2;   // XOR swizzle on float idx bits 2..4

  const float* xsrc = x + (size_t)(rowBase + srow) * D + w * KCH + scol;
  float* mybuf0 = &xbuf[w][0][0][0];
  float* mybuf1 = &xbuf[w][1][0][0];

  // loop-invariant swizzled ds_write indices for the 8 row-groups
  const int sw0 = (0 * 4 + srow) * 64 + (scol ^ (((0 * 4 + srow) & 7) << 2));
  const int sw1 = (1 * 4 + srow) * 64 + (scol ^ (((1 * 4 + srow) & 7) << 2));
  const int sw2 = (2 * 4 + srow) * 64 + (scol ^ (((2 * 4 + srow) & 7) << 2));
  const int sw3 = (3 * 4 + srow) * 64 + (scol ^ (((3 * 4 + srow) & 7) << 2));
  const int sw4 = (4 * 4 + srow) * 64 + (scol ^ (((4 * 4 + srow) & 7) << 2));
  const int sw5 = (5 * 4 + srow) * 64 + (scol ^ (((5 * 4 + srow) & 7) << 2));
  const int sw6 = (6 * 4 + srow) * 64 + (scol ^ (((6 * 4 + srow) & 7) << 2));
  const int sw7 = (7 * 4 + srow) * 64 + (scol ^ (((7 * 4 + srow) & 7) << 2));

  float4 g0, g1, g2, g3, g4, g5, g6, g7;

#define LDG(C)                                                \
  g0 = *(const float4*)(xsrc + 0 * 16384 + (C) * CH);         \
  g1 = *(const float4*)(xsrc + 1 * 16384 + (C) * CH);         \
  g2 = *(const float4*)(xsrc + 2 * 16384 + (C) * CH);         \
  g3 = *(const float4*)(xsrc + 3 * 16384 + (C) * CH);         \
  g4 = *(const float4*)(xsrc + 4 * 16384 + (C) * CH);         \
  g5 = *(const float4*)(xsrc + 5 * 16384 + (C) * CH);         \
  g6 = *(const float4*)(xsrc + 6 * 16384 + (C) * CH);         \
  g7 = *(const float4*)(xsrc + 7 * 16384 + (C) * CH);

#define STW(BUF)                                              \
  *(float4*)&(BUF)[sw0] = g0; *(float4*)&(BUF)[sw1] = g1;     \
  *(float4*)&(BUF)[sw2] = g2; *(float4*)&(BUF)[sw3] = g3;     \
  *(float4*)&(BUF)[sw4] = g4; *(float4*)&(BUF)[sw5] = g5;     \
  *(float4*)&(BUF)[sw6] = g6; *(float4*)&(BUF)[sw7] = g7;

#define COMPUTE(BUF, C)                                                       \
  _Pragma("unroll")                                                           \
  for (int s_ = 0; s_ < 4; ++s_) {                                            \
    const int kf_ = 16 * s_ + 8 * ahalf;                                      \
    const float4 xa0 = *(const float4*)&(BUF)[arow * 64 + (kf_ ^ swzr)];      \
    const float4 xa1 = *(const float4*)&(BUF)[arow * 64 + ((kf_ + 4) ^ swzr)];\
    const size_t fi = (size_t)(w * 64 + (C) * 4 + s_) * 128 + lane;           \
    const f16x8 bh0 = WH[fi], bh1 = WH[fi + 64];                              \
    const f16x8 bl0 = WL[fi], bl1 = WL[fi + 64];                              \
    KSTEP(xa0, xa1, bh0, bh1, bl0, bl1)                                       \
  }

  f32x16 acc00, acc01, acc10, acc11;
#pragma unroll
  for (int r = 0; r < 16; ++r) { acc00[r] = 0.0f; acc01[r] = 0.0f; acc10[r] = 0.0f; acc11[r] = 0.0f; }

  LDG(0)
  STW(mybuf0)
  for (int cc = 0; cc < NCH; cc += 2) {
    LDG(cc + 1)
    COMPUTE(mybuf0, cc)
    STW(mybuf1)
    if (cc + 2 < NCH) { LDG(cc + 2) }
    COMPUTE(mybuf1, cc + 1)
    if (cc + 2 < NCH) { STW(mybuf0) }
  }

  // C/D layout (HW-verified m74/m101): col = 32t+(lane&31),
  // row = (reg&3) + 8*(reg>>2) + 4*(lane>>5). Buffers dead; reuse xbuf as
  // 4 planes of [32][64] logit partials (plane stride 4096 floats).
  float* lsw = &xbuf[0][0][0][0] + w * 4096;
#pragma unroll
  for (int r = 0; r < 16; ++r) {
    const int lrow = (r & 3) + 8 * (r >> 2) + 4 * ahalf;
    lsw[lrow * 64 + arow]      = acc00[r] + acc10[r] * (1.0f / 4096.0f);
    lsw[lrow * 64 + 32 + arow] = acc01[r] + acc11[r] * (1.0f / 4096.0f);
  }
  __syncthreads();

  // Fold 4 K-quarter planes, deterministic ((q0+q1)+q2)+q3 (= round-2 order).
  {
    float* base = &xbuf[0][0][0][0];
#pragma unroll
    for (int j = 0; j < 8; ++j) {
      const int idx = threadIdx.x + 256 * j;  // 2048 = 32x64
      base[idx] = ((base[idx] + base[idx + 4096]) + base[idx + 8192]) + base[idx + 12288];
    }
  }
  __syncthreads();

  // Softmax + top-2 + RNG (bit-exact round-2 logic). Wave w: rows w*8..w*8+7.
  const float* lsum0 = &xbuf[0][0][0][0];
  for (int rr = 0; rr < 8; ++rr) {
    const int lrow = w * 8 + rr;
    const int grow = rowBase + lrow;
    const float l = lsum0[lrow * 64 + lane];

    float m = l;
#pragma unroll
    for (int off = 32; off; off >>= 1) m = fmaxf(m, __shfl_xor(m, off));
    const float ex = expf(l - m);
    float ssum = ex;
#pragma unroll
    for (int off = 32; off; off >>= 1) ssum += __shfl_xor(ssum, off);
    ssum = __shfl(ssum, 0);  // single denominator like the reference
    const float gate = ex / ssum;

    float v = gate; int id = lane;
#pragma unroll
    for (int off = 32; off; off >>= 1) {
      float vo = __shfl_xor(v, off); int io = __shfl_xor(id, off);
      if (vo > v || (vo == v && io < id)) { v = vo; id = io; }
    }
    const float g1v = v; const int e1 = id;
    const float gate2 = (lane == e1) ? -1.0f : gate;
    v = gate2; id = lane;
#pragma unroll
    for (int off = 32; off; off >>= 1) {
      float vo = __shfl_xor(v, off); int io = __shfl_xor(id, off);
      if (vo > v || (vo == v && io < id)) { v = vo; id = io; }
    }
    const float g2v = v; const int e2 = id;

    if (lane == 0) {
      const float denom = g1v + g2v;
      const float g1n = g1v / denom;
      const float g2n = g2v / denom;
      const uint32_t bits = threefry_bits(grow);
      const float rnd = __uint_as_float((bits >> 9) | 0x3f800000u) - 1.0f;
      E1[grow] = e1; E2[grow] = e2;
      WANT[grow] = (rnd < 2.0f * g2n) ? 1 : 0;
      G1[grow] = g1n; G2[grow] = g2n;
    }
  }
}

// ---- K2: per-block (128 rows) local ranks + histograms (unchanged).
__global__ __launch_bounds__(K2ROWS) void k2_rank(const int* __restrict__ E1,
                                                  const int* __restrict__ E2,
                                                  const int* __restrict__ WANT,
                                                  int* __restrict__ LR1, int* __restrict__ LR2,
                                                  int* __restrict__ H1, int* __restrict__ H2) {
  __shared__ unsigned char s1[K2ROWS], s2[K2ROWS];
  __shared__ int h1[NE], h2[NE];
  const int b = blockIdx.x, t = threadIdx.x;
  const int r = b * K2ROWS + t;
  if (t < NE) { h1[t] = 0; h2[t] = 0; }
  const int e1 = E1[r];
  const int e2 = WANT[r] ? E2[r] : NE;  // sentinel = excluded
  s1[t] = (unsigned char)e1;
  s2[t] = (unsigned char)e2;
  __syncthreads();
  int r1 = 0, r2 = 0;
  for (int j = 0; j < t; ++j) {
    r1 += (s1[j] == e1);
    r2 += (s2[j] == e2);
  }
  LR1[r] = r1; LR2[r] = r2;
  atomicAdd(&h1[e1], 1);
  if (e2 < NE) atomicAdd(&h2[e2], 1);
  __syncthreads();
  if (t < NE) { H1[b * NE + t] = h1[t]; H2[b * NE + t] = h2[t]; }
}

// ---- K3: prefix over blocks per expert, LDS-staged (verified round 3).
__global__ __launch_bounds__(256) void k3_prefix(const int* __restrict__ H1,
                                                 const int* __restrict__ H2,
                                                 int* __restrict__ OFF1, int* __restrict__ OFF2,
                                                 int* __restrict__ REM2) {
  __shared__ int sh1[NB * NE], sh2[NB * NE];  // 32 KB + 32 KB
  const int t = threadIdx.x;
#pragma unroll
  for (int j = 0; j < 8; ++j) {
    const int i4 = t + 256 * j;  // 2048 int4 = 8192 ints
    ((int4*)sh1)[i4] = ((const int4*)H1)[i4];
    ((int4*)sh2)[i4] = ((const int4*)H2)[i4];
  }
  __syncthreads();
  if (t < NE) {
    int run1 = 0, run2 = 0;
    for (int b = 0; b < NB; ++b) {
      OFF1[b * NE + t] = run1; run1 += sh1[b * NE + t];
      OFF2[b * NE + t] = run2; run2 += sh2[b * NE + t];
    }
    REM2[t] = CAP - min(run1, CAP);
  }
}

// ---- K4: dense writer, lane = expert column (verified round 3).
__global__ __launch_bounds__(256) void k4_write(const int* __restrict__ E1,
                                                const int* __restrict__ E2,
                                                const int* __restrict__ WANT,
                                                const float* __restrict__ G1,
                                                const float* __restrict__ G2,
                                                const int* __restrict__ LR1,
                                                const int* __restrict__ LR2,
                                                const int* __restrict__ OFF1,
                                                const int* __restrict__ OFF2,
                                                const int* __restrict__ REM2,
                                                float* __restrict__ out) {
  const int w = threadIdx.x >> 6, lane = threadIdx.x & 63;
  const int rowBase = blockIdx.x * 16 + w * 4;  // grid 1024, 4 rows/wave
#pragma unroll
  for (int i = 0; i < 4; ++i) {
    const int r = rowBase + i;
    const int b = r / K2ROWS;
    const int e1 = E1[r];
    const int pos1 = OFF1[b * NE + e1] + LR1[r] + 1;
    float val = 0.0f;
    if (lane == e1 && pos1 <= CAP) val = G1[r];
    if (WANT[r]) {
      const int e2 = E2[r];
      const int pos2 = OFF2[b * NE + e2] + LR2[r] + 1;
      if (lane == e2 && pos2 <= REM2[e2]) val = G2[r];
    }
    out[(size_t)r * NE + lane] = val;
  }
}

extern "C" void kernel_launch(void* const* d_in, const int* in_sizes, int n_in,
                              void* d_out, int out_size, void* d_ws, size_t ws_size,
                              hipStream_t stream) {
  const float* x  = (const float*)d_in[0];
  const float* Wg = (const float*)d_in[1];
  float* out = (float*)d_out;
  char* ws = (char*)d_ws;

  size_t off = 0;
  int*   E1   = (int*)(ws + off);   off += (size_t)S * 4;
  int*   E2   = (int*)(ws + off);   off += (size_t)S * 4;
  int*   WANT = (int*)(ws + off);   off += (size_t)S * 4;
  float* G1   = (float*)(ws + off); off += (size_t)S * 4;
  float* G2   = (float*)(ws + off); off += (size_t)S * 4;
  int*   LR1  = (int*)(ws + off);   off += (size_t)S * 4;
  int*   LR2  = (int*)(ws + off);   off += (size_t)S * 4;
  int*   H1   = (int*)(ws + off);   off += (size_t)NB * NE * 4;
  int*   H2   = (int*)(ws + off);   off += (size_t)NB * NE * 4;
  int*   OFF1 = (int*)(ws + off);   off += (size_t)NB * NE * 4;
  int*   OFF2 = (int*)(ws + off);   off += (size_t)NB * NE * 4;
  int*   REM2 = (int*)(ws + off);   off += (size_t)NE * 4;
  f16x8* WH   = (f16x8*)(ws + off); off += (size_t)NKS * 2 * 64 * sizeof(f16x8);  // 512 KB
  f16x8* WL   = (f16x8*)(ws + off); off += (size_t)NKS * 2 * 64 * sizeof(f16x8);  // 512 KB

  k0_packw<<<128, 256, 0, stream>>>(Wg, WH, WL);
  k1_fused<<<S / 32, 256, 0, stream>>>(x, WH, WL, E1, E2, WANT, G1, G2);
  k2_rank<<<NB, K2ROWS, 0, stream>>>(E1, E2, WANT, LR1, LR2, H1, H2);
  k3_prefix<<<1, 256, 0, stream>>>(H1, H2, OFF1, OFF2, REM2);
  k4_write<<<S / 16, 256, 0, stream>>>(E1, E2, WANT, G1, G2, LR1, LR2, OFF1, OFF2, REM2, out);
}

// Round 8
// 402.875 us; speedup vs baseline: 1.0341x; 1.0341x over previous
//
#include <hip/hip_runtime.h>
#include <stdint.h>

#define S 16384
#define D 4096
#define NE 64
#define CAP 320
#define KSPLIT 4           // K-quarter per block (partials)
#define KCH 256            // K per wave (sixteenth): A held in regs as f16
#define NKS (D / 16)       // 256 total k-steps
#define K2ROWS 128
#define NB (S / K2ROWS)    // 128

typedef _Float16 f16x8 __attribute__((ext_vector_type(8)));
typedef float f32x16 __attribute__((ext_vector_type(16)));

__device__ __forceinline__ uint32_t rotl32(uint32_t v, int n) {
  return (v << n) | (v >> (32 - n));
}

// Bit-exact jax threefry for jax.random.uniform(jax.random.key(1), (S,), f32)
// under jax_threefry_partitionable=True. (Verified passing, absmax 0.0.)
__device__ uint32_t threefry_bits(int i) {
  const uint32_t k0 = 0u, k1 = 1u;
  const uint32_t ks2 = k0 ^ k1 ^ 0x1BD11BDAu;
  uint32_t x0 = 0u + k0;
  uint32_t x1 = (uint32_t)i + k1;
#define TFR(R) { x0 += x1; x1 = rotl32(x1, R); x1 ^= x0; }
  TFR(13) TFR(15) TFR(26) TFR(6)
  x0 += k1;  x1 += ks2 + 1u;
  TFR(17) TFR(29) TFR(16) TFR(24)
  x0 += ks2; x1 += k0 + 2u;
  TFR(13) TFR(15) TFR(26) TFR(6)
  x0 += k0;  x1 += k1 + 3u;
  TFR(17) TFR(29) TFR(16) TFR(24)
  x0 += k1;  x1 += ks2 + 4u;
  TFR(13) TFR(15) TFR(26) TFR(6)
  x0 += ks2; x1 += k0 + 5u;
#undef TFR
  return x0 ^ x1;
}

// ---- k0: pack W (64x4096 f32) into fp16 hi/lo MFMA B-fragments (verified).
// n-tile t, k-step ks: lane l holds col = 32t+(l&31), k = 16*ks + 8*(l>>5)+j.
// A uses the same k-bijection. Split: w = wh + wl*2^-12 (exact residual).
__global__ __launch_bounds__(256) void k0_packw(const float* __restrict__ Wg,
                                                f16x8* __restrict__ WH,
                                                f16x8* __restrict__ WL) {
  const int tid = blockIdx.x * 256 + threadIdx.x;  // 32768 = 256 ks * 2 t * 64 lanes
  const int lane = tid & 63;
  const int t = (tid >> 6) & 1;
  const int ks = tid >> 7;
  const int col = 32 * t + (lane & 31);
  const int k0 = ks * 16 + 8 * (lane >> 5);
  const float* wp = Wg + (size_t)col * D + k0;
  f16x8 h, l;
#pragma unroll
  for (int j = 0; j < 8; ++j) {
    const float w = wp[j];
    const _Float16 wh = (_Float16)w;
    const float r = (w - (float)wh) * 4096.0f;  // exact in f32
    h[j] = wh;
    l[j] = (_Float16)r;
  }
  WH[tid] = h;
  WL[tid] = l;
}

// fp32 -> fp16 hi/lo split of one float into frag slot J (same arithmetic as
// all passing rounds).
#define CVT1(AH, AL, J, F)                                             \
  { const float f_ = (F); const _Float16 h_ = (_Float16)f_;            \
    (AH)[J] = h_; (AL)[J] = (_Float16)((f_ - (float)h_) * 4096.0f); }

// Convert float4 pair -> one k-step's A fragments (8 elems).
#define CVT8(SD, XA, XB)                                               \
  CVT1(ah##SD, al##SD, 0, (XA).x) CVT1(ah##SD, al##SD, 1, (XA).y)      \
  CVT1(ah##SD, al##SD, 2, (XA).z) CVT1(ah##SD, al##SD, 3, (XA).w)      \
  CVT1(ah##SD, al##SD, 4, (XB).x) CVT1(ah##SD, al##SD, 5, (XB).y)      \
  CVT1(ah##SD, al##SD, 6, (XB).z) CVT1(ah##SD, al##SD, 7, (XB).w)

// One k-step: 4 B loads (L2) + 6 MFMAs, pre-converted A (no VALU, no x-deps).
#define BSTEP(SD, KSG)                                                        \
  {                                                                           \
    const size_t fi = (size_t)(KSG) * 128 + lane;                             \
    const f16x8 bh0 = WH[fi], bh1 = WH[fi + 64];                              \
    const f16x8 bl0 = WL[fi], bl1 = WL[fi + 64];                              \
    acc00 = __builtin_amdgcn_mfma_f32_32x32x16_f16(ah##SD, bh0, acc00, 0, 0, 0); \
    acc10 = __builtin_amdgcn_mfma_f32_32x32x16_f16(al##SD, bh0, acc10, 0, 0, 0); \
    acc10 = __builtin_amdgcn_mfma_f32_32x32x16_f16(ah##SD, bl0, acc10, 0, 0, 0); \
    acc01 = __builtin_amdgcn_mfma_f32_32x32x16_f16(ah##SD, bh1, acc01, 0, 0, 0); \
    acc11 = __builtin_amdgcn_mfma_f32_32x32x16_f16(al##SD, bh1, acc11, 0, 0, 0); \
    acc11 = __builtin_amdgcn_mfma_f32_32x32x16_f16(ah##SD, bl1, acc11, 0, 0, 0); \
  }

// ---- k1: logits GEMM partials, vmcnt-stream-decoupled.
// Diagnosis (r2-r6): x loads (HBM ~900cy) and WH/WL loads (L2 ~200cy) share
// the per-wave vmcnt FIFO; s_waitcnt drains OLDEST first, so every per-kstep
// B-wait also drained in-flight x prefetches -> one full latency per kstep,
// immune to occupancy (r4), ILP (r5), and LDS staging (r6).
// Fix: per half (8 ksteps), burst-load ALL x (16 float4, one drain), convert
// once to resident fp16 hi/lo frags, then a pure B-stream MFMA loop whose
// FIFO holds only fast L2 loads. sched_barrier(0) pins B loads out of the
// burst region. Wave = 32 rows x 256 K (sixteenth); block = 4 waves =
// K-quarter; LDS-fold -> part[4][S][64]; k1b sums quarters (round-0 order).
__global__ __launch_bounds__(256) void k1_logits(const float* __restrict__ x,
                                                 const f16x8* __restrict__ WH,
                                                 const f16x8* __restrict__ WL,
                                                 float* __restrict__ part) {
  __shared__ float lsum[4][32][64];  // 32 KB
  const int w = threadIdx.x >> 6;
  const int lane = threadIdx.x & 63;
  const int rg = blockIdx.x >> 2;   // row group (512)
  const int kq = blockIdx.x & 3;    // K-quarter
  const int rowBase = rg * 32;
  const int arow = lane & 31;
  const int ahalf = lane >> 5;
  const int sixt = kq * 4 + w;      // K-sixteenth 0..15
  const float4* xq = (const float4*)(x + (size_t)(rowBase + arow) * D + sixt * KCH + ahalf * 8);
  const int ks0 = sixt * 16;        // global k-step base (16 per sixteenth)

  f32x16 acc00, acc01, acc10, acc11;
#pragma unroll
  for (int r = 0; r < 16; ++r) { acc00[r] = 0.0f; acc01[r] = 0.0f; acc10[r] = 0.0f; acc11[r] = 0.0f; }

  f16x8 ah0, ah1, ah2, ah3, ah4, ah5, ah6, ah7;
  f16x8 al0, al1, al2, al3, al4, al5, al6, al7;

  // ================= half 0 (ksteps 0..7) =================
  {
    // burst: 16 independent HBM loads (deep MLP, single FIFO drain at convert)
    const float4 x0 = xq[0],  x1 = xq[1],  x2 = xq[4],  x3 = xq[5];
    const float4 x4 = xq[8],  x5 = xq[9],  x6 = xq[12], x7 = xq[13];
    const float4 x8 = xq[16], x9 = xq[17], x10 = xq[20], x11 = xq[21];
    const float4 x12 = xq[24], x13 = xq[25], x14 = xq[28], x15 = xq[29];
    CVT8(0, x0, x1)   CVT8(1, x2, x3)   CVT8(2, x4, x5)   CVT8(3, x6, x7)
    CVT8(4, x8, x9)   CVT8(5, x10, x11) CVT8(6, x12, x13) CVT8(7, x14, x15)
  }
  __builtin_amdgcn_sched_barrier(0);  // keep B loads out of the x-burst FIFO
  BSTEP(0, ks0 + 0) BSTEP(1, ks0 + 1) BSTEP(2, ks0 + 2) BSTEP(3, ks0 + 3)
  BSTEP(4, ks0 + 4) BSTEP(5, ks0 + 5) BSTEP(6, ks0 + 6) BSTEP(7, ks0 + 7)

  // ================= half 1 (ksteps 8..15) =================
  {
    const float4 x0 = xq[32], x1 = xq[33], x2 = xq[36], x3 = xq[37];
    const float4 x4 = xq[40], x5 = xq[41], x6 = xq[44], x7 = xq[45];
    const float4 x8 = xq[48], x9 = xq[49], x10 = xq[52], x11 = xq[53];
    const float4 x12 = xq[56], x13 = xq[57], x14 = xq[60], x15 = xq[61];
    CVT8(0, x0, x1)   CVT8(1, x2, x3)   CVT8(2, x4, x5)   CVT8(3, x6, x7)
    CVT8(4, x8, x9)   CVT8(5, x10, x11) CVT8(6, x12, x13) CVT8(7, x14, x15)
  }
  __builtin_amdgcn_sched_barrier(0);
  BSTEP(0, ks0 + 8)  BSTEP(1, ks0 + 9)  BSTEP(2, ks0 + 10) BSTEP(3, ks0 + 11)
  BSTEP(4, ks0 + 12) BSTEP(5, ks0 + 13) BSTEP(6, ks0 + 14) BSTEP(7, ks0 + 15)

  // C/D layout (HW-verified m74/m101): col = 32t+(lane&31),
  // row = (reg&3) + 8*(reg>>2) + 4*(lane>>5).
#pragma unroll
  for (int r = 0; r < 16; ++r) {
    const int lrow = (r & 3) + 8 * (r >> 2) + 4 * ahalf;
    lsum[w][lrow][arow]      = acc00[r] + acc10[r] * (1.0f / 4096.0f);
    lsum[w][lrow][32 + arow] = acc01[r] + acc11[r] * (1.0f / 4096.0f);
  }
  __syncthreads();

  // Fold 4 sixteenth-planes (deterministic ((w0+w1)+w2)+w3), write K-quarter
  // partial; idx = tid + 256*j spans 32x64 row-major -> coalesced.
  {
    const float* p0 = &lsum[0][0][0];
#pragma unroll
    for (int j = 0; j < 8; ++j) {
      const int idx = threadIdx.x + 256 * j;
      const float v = ((p0[idx] + p0[idx + 2048]) + p0[idx + 4096]) + p0[idx + 6144];
      part[((size_t)kq * S + rowBase) * NE + idx] = v;
    }
  }
}

// ---- k1b: reduce K-quarter partials, softmax, top-2, RNG (round-0-verified
// body, c<4). One wave per row, lane = expert.
__global__ __launch_bounds__(256) void k1b_reduce(const float* __restrict__ part,
                                                  int* __restrict__ E1, int* __restrict__ E2,
                                                  int* __restrict__ WANT,
                                                  float* __restrict__ G1, float* __restrict__ G2) {
  const int row = blockIdx.x * 4 + (threadIdx.x >> 6);
  const int lane = threadIdx.x & 63;
  float l = 0.0f;
#pragma unroll
  for (int c = 0; c < KSPLIT; ++c)
    l += part[((size_t)c * S + row) * NE + lane];

  float m = l;
#pragma unroll
  for (int off = 32; off; off >>= 1) m = fmaxf(m, __shfl_xor(m, off));
  const float ex = expf(l - m);
  float ssum = ex;
#pragma unroll
  for (int off = 32; off; off >>= 1) ssum += __shfl_xor(ssum, off);
  ssum = __shfl(ssum, 0);  // single denominator like the reference
  const float gate = ex / ssum;

  float v = gate; int id = lane;
#pragma unroll
  for (int off = 32; off; off >>= 1) {
    float vo = __shfl_xor(v, off); int io = __shfl_xor(id, off);
    if (vo > v || (vo == v && io < id)) { v = vo; id = io; }
  }
  const float g1 = v; const int e1 = id;
  const float gate2 = (lane == e1) ? -1.0f : gate;
  v = gate2; id = lane;
#pragma unroll
  for (int off = 32; off; off >>= 1) {
    float vo = __shfl_xor(v, off); int io = __shfl_xor(id, off);
    if (vo > v || (vo == v && io < id)) { v = vo; id = io; }
  }
  const float g2 = v; const int e2 = id;

  if (lane == 0) {
    const float denom = g1 + g2;
    const float g1n = g1 / denom;
    const float g2n = g2 / denom;
    const uint32_t bits = threefry_bits(row);
    const float rnd = __uint_as_float((bits >> 9) | 0x3f800000u) - 1.0f;
    E1[row] = e1; E2[row] = e2;
    WANT[row] = (rnd < 2.0f * g2n) ? 1 : 0;
    G1[row] = g1n; G2[row] = g2n;
  }
}

// ---- K2: per-block (128 rows) local ranks + histograms (unchanged).
__global__ __launch_bounds__(K2ROWS) void k2_rank(const int* __restrict__ E1,
                                                  const int* __restrict__ E2,
                                                  const int* __restrict__ WANT,
                                                  int* __restrict__ LR1, int* __restrict__ LR2,
                                                  int* __restrict__ H1, int* __restrict__ H2) {
  __shared__ unsigned char s1[K2ROWS], s2[K2ROWS];
  __shared__ int h1[NE], h2[NE];
  const int b = blockIdx.x, t = threadIdx.x;
  const int r = b * K2ROWS + t;
  if (t < NE) { h1[t] = 0; h2[t] = 0; }
  const int e1 = E1[r];
  const int e2 = WANT[r] ? E2[r] : NE;  // sentinel = excluded
  s1[t] = (unsigned char)e1;
  s2[t] = (unsigned char)e2;
  __syncthreads();
  int r1 = 0, r2 = 0;
  for (int j = 0; j < t; ++j) {
    r1 += (s1[j] == e1);
    r2 += (s2[j] == e2);
  }
  LR1[r] = r1; LR2[r] = r2;
  atomicAdd(&h1[e1], 1);
  if (e2 < NE) atomicAdd(&h2[e2], 1);
  __syncthreads();
  if (t < NE) { H1[b * NE + t] = h1[t]; H2[b * NE + t] = h2[t]; }
}

// ---- K3: prefix over blocks per expert, LDS-staged (verified round 3).
__global__ __launch_bounds__(256) void k3_prefix(const int* __restrict__ H1,
                                                 const int* __restrict__ H2,
                                                 int* __restrict__ OFF1, int* __restrict__ OFF2,
                                                 int* __restrict__ REM2) {
  __shared__ int sh1[NB * NE], sh2[NB * NE];  // 32 KB + 32 KB
  const int t = threadIdx.x;
#pragma unroll
  for (int j = 0; j < 8; ++j) {
    const int i4 = t + 256 * j;  // 2048 int4 = 8192 ints
    ((int4*)sh1)[i4] = ((const int4*)H1)[i4];
    ((int4*)sh2)[i4] = ((const int4*)H2)[i4];
  }
  __syncthreads();
  if (t < NE) {
    int run1 = 0, run2 = 0;
    for (int b = 0; b < NB; ++b) {
      OFF1[b * NE + t] = run1; run1 += sh1[b * NE + t];
      OFF2[b * NE + t] = run2; run2 += sh2[b * NE + t];
    }
    REM2[t] = CAP - min(run1, CAP);
  }
}

// ---- K4: dense writer, lane = expert column (verified round 3).
__global__ __launch_bounds__(256) void k4_write(const int* __restrict__ E1,
                                                const int* __restrict__ E2,
                                                const int* __restrict__ WANT,
                                                const float* __restrict__ G1,
                                                const float* __restrict__ G2,
                                                const int* __restrict__ LR1,
                                                const int* __restrict__ LR2,
                                                const int* __restrict__ OFF1,
                                                const int* __restrict__ OFF2,
                                                const int* __restrict__ REM2,
                                                float* __restrict__ out) {
  const int w = threadIdx.x >> 6, lane = threadIdx.x & 63;
  const int rowBase = blockIdx.x * 16 + w * 4;  // grid 1024, 4 rows/wave
#pragma unroll
  for (int i = 0; i < 4; ++i) {
    const int r = rowBase + i;
    const int b = r / K2ROWS;
    const int e1 = E1[r];
    const int pos1 = OFF1[b * NE + e1] + LR1[r] + 1;
    float val = 0.0f;
    if (lane == e1 && pos1 <= CAP) val = G1[r];
    if (WANT[r]) {
      const int e2 = E2[r];
      const int pos2 = OFF2[b * NE + e2] + LR2[r] + 1;
      if (lane == e2 && pos2 <= REM2[e2]) val = G2[r];
    }
    out[(size_t)r * NE + lane] = val;
  }
}

extern "C" void kernel_launch(void* const* d_in, const int* in_sizes, int n_in,
                              void* d_out, int out_size, void* d_ws, size_t ws_size,
                              hipStream_t stream) {
  const float* x  = (const float*)d_in[0];
  const float* Wg = (const float*)d_in[1];
  float* out = (float*)d_out;
  char* ws = (char*)d_ws;

  size_t off = 0;
  float* part = (float*)ws;         off += (size_t)KSPLIT * S * NE * 4;  // 16 MB
  int*   E1   = (int*)(ws + off);   off += (size_t)S * 4;
  int*   E2   = (int*)(ws + off);   off += (size_t)S * 4;
  int*   WANT = (int*)(ws + off);   off += (size_t)S * 4;
  float* G1   = (float*)(ws + off); off += (size_t)S * 4;
  float* G2   = (float*)(ws + off); off += (size_t)S * 4;
  int*   LR1  = (int*)(ws + off);   off += (size_t)S * 4;
  int*   LR2  = (int*)(ws + off);   off += (size_t)S * 4;
  int*   H1   = (int*)(ws + off);   off += (size_t)NB * NE * 4;
  int*   H2   = (int*)(ws + off);   off += (size_t)NB * NE * 4;
  int*   OFF1 = (int*)(ws + off);   off += (size_t)NB * NE * 4;
  int*   OFF2 = (int*)(ws + off);   off += (size_t)NB * NE * 4;
  int*   REM2 = (int*)(ws + off);   off += (size_t)NE * 4;
  f16x8* WH   = (f16x8*)(ws + off); off += (size_t)NKS * 2 * 64 * sizeof(f16x8);  // 512 KB
  f16x8* WL   = (f16x8*)(ws + off); off += (size_t)NKS * 2 * 64 * sizeof(f16x8);  // 512 KB

  k0_packw<<<128, 256, 0, stream>>>(Wg, WH, WL);
  k1_logits<<<(S / 32) * KSPLIT, 256, 0, stream>>>(x, WH, WL, part);
  k1b_reduce<<<S / 4, 256, 0, stream>>>(part, E1, E2, WANT, G1, G2);
  k2_rank<<<NB, K2ROWS, 0, stream>>>(E1, E2, WANT, LR1, LR2, H1, H2);
  k3_prefix<<<1, 256, 0, stream>>>(H1, H2, OFF1, OFF2, REM2);
  k4_write<<<S / 16, 256, 0, stream>>>(E1, E2, WANT, G1, G2, LR1, LR2, OFF1, OFF2, REM2, out);
}